// Round 1
// baseline (536.341 us; speedup 1.0000x reference)
//
#include <hip/hip_runtime.h>

// MultiIndexSelect: out[to_k[i]] = mat_k[from_k[i]], k=0..2
// L = 400000 rows per segment, D = 64 fp32 (256 B per row).
// 16 threads per row, float4 per thread -> one fully-coalesced 256 B
// segment per row for both the gather read and the scatter write.

#define L_ROWS 400000
#define VEC_PER_ROW 16   // 64 floats / 4 per float4

__global__ __launch_bounds__(256) void multi_index_select_kernel(
    const float4* __restrict__ mat0,
    const float4* __restrict__ mat1,
    const float4* __restrict__ mat2,
    const int*    __restrict__ from0,
    const int*    __restrict__ from1,
    const int*    __restrict__ from2,
    const int*    __restrict__ to0,
    const int*    __restrict__ to1,
    const int*    __restrict__ to2,
    float4*       __restrict__ out)
{
    long long tid = (long long)blockIdx.x * blockDim.x + threadIdx.x;
    int row = (int)(tid >> 4);      // global row index in [0, 3L)
    int col = (int)(tid & 15);      // float4 index within the row
    if (row >= 3 * L_ROWS) return;

    const float4* mat;
    const int* from;
    const int* to;
    int r;
    if (row < L_ROWS) {
        mat = mat0; from = from0; to = to0; r = row;
    } else if (row < 2 * L_ROWS) {
        mat = mat1; from = from1; to = to1; r = row - L_ROWS;
    } else {
        mat = mat2; from = from2; to = to2; r = row - 2 * L_ROWS;
    }

    int src = from[r];   // broadcast across the 16 lanes of this row
    int dst = to[r];

    out[(size_t)dst * VEC_PER_ROW + col] = mat[(size_t)src * VEC_PER_ROW + col];
}

extern "C" void kernel_launch(void* const* d_in, const int* in_sizes, int n_in,
                              void* d_out, int out_size, void* d_ws, size_t ws_size,
                              hipStream_t stream) {
    const float4* mat0 = (const float4*)d_in[0];
    const float4* mat1 = (const float4*)d_in[1];
    const float4* mat2 = (const float4*)d_in[2];
    const int* from0 = (const int*)d_in[3];
    const int* from1 = (const int*)d_in[4];
    const int* from2 = (const int*)d_in[5];
    const int* to0   = (const int*)d_in[6];
    const int* to1   = (const int*)d_in[7];
    const int* to2   = (const int*)d_in[8];
    float4* out = (float4*)d_out;

    const long long total_threads = (long long)3 * L_ROWS * VEC_PER_ROW;  // 19.2M
    const int block = 256;
    const int grid = (int)((total_threads + block - 1) / block);          // 75000

    multi_index_select_kernel<<<grid, block, 0, stream>>>(
        mat0, mat1, mat2, from0, from1, from2, to0, to1, to2, out);
}